// Round 16
// baseline (1219.698 us; speedup 1.0000x reference)
//
#include <hip/hip_runtime.h>
#include <stdint.h>

#define SEQ 2048
#define DM 4096
#define NHEADS 16
#define DHEAD 256
#define DFF 16384

typedef __attribute__((ext_vector_type(8))) short short8;
typedef __attribute__((ext_vector_type(4))) float f32x4;
typedef __attribute__((ext_vector_type(4))) float float4v;
typedef __attribute__((ext_vector_type(4))) unsigned short ushort4v;
typedef __attribute__((ext_vector_type(8))) unsigned short ushort8v;

__device__ __forceinline__ unsigned short f2b(float f) {
    uint32_t u = __builtin_bit_cast(uint32_t, f);
    u = (u + 0x7FFFu + ((u >> 16) & 1u)) >> 16;
    return (unsigned short)u;
}

__device__ __forceinline__ void gload_lds16(const void* g, void* l) {
    __builtin_amdgcn_global_load_lds((const __attribute__((address_space(1))) void*)g,
                                     (__attribute__((address_space(3))) void*)l, 16, 0, 0);
}

// ---------------- pre: LN + ALL weight transposes in one flat-grid launch ----------------
__global__ __launch_bounds__(256) void pre_all(
    const float* __restrict__ x, const float* __restrict__ sc, const float* __restrict__ of,
    unsigned short* __restrict__ h,
    const float* __restrict__ wq, const float* __restrict__ wk, const float* __restrict__ wv,
    const float* __restrict__ wo, const float* __restrict__ wf1, const float* __restrict__ wf2,
    unsigned short* __restrict__ dqkv, unsigned short* __restrict__ dwo,
    unsigned short* __restrict__ df1, unsigned short* __restrict__ df2) {
    __shared__ unsigned short tl[64 * 66];
    __shared__ float rs[4], rs2[4];
    int b = blockIdx.x;
    if (b < SEQ) {
        int row = b;
        int tid = threadIdx.x, lane = tid & 63, wave = tid >> 6;
        const float4v* xr = (const float4v*)(x + (size_t)row * DM);
        float4v v[4];
        float s = 0.f, s2 = 0.f;
#pragma unroll
        for (int i = 0; i < 4; ++i) {
            v[i] = xr[tid + i * 256];
#pragma unroll
            for (int j = 0; j < 4; ++j) { s += v[i][j]; s2 += v[i][j] * v[i][j]; }
        }
#pragma unroll
        for (int o = 1; o < 64; o <<= 1) { s += __shfl_xor(s, o); s2 += __shfl_xor(s2, o); }
        if (lane == 0) { rs[wave] = s; rs2[wave] = s2; }
        __syncthreads();
        s = rs[0] + rs[1] + rs[2] + rs[3];
        s2 = rs2[0] + rs2[1] + rs2[2] + rs2[3];
        float mean = s * (1.0f / DM);
        float var = s2 * (1.0f / DM) - mean * mean;
        float inv = rsqrtf(var + 1e-5f);
#pragma unroll
        for (int i = 0; i < 4; ++i) {
            int c = (tid + i * 256) * 4;
            ushort4v o4;
#pragma unroll
            for (int j = 0; j < 4; ++j)
                o4[j] = f2b((v[i][j] - mean) * inv * sc[c + j] + of[c + j]);
            *(ushort4v*)(h + (size_t)row * DM + c) = o4;
        }
        return;
    }
    b -= SEQ;
    const float* src;
    unsigned short* dst;
    int ldS, ldD, tx;
    if (b < 12288) {
        int w = b >> 12;
        b &= 4095;
        src = (w == 0) ? wq : (w == 1) ? wk : wv;
        dst = dqkv + (size_t)w * DM * DM;
        ldS = DM; ldD = DM; tx = 64;
    } else if (b < 16384) {
        b -= 12288; src = wo; dst = dwo; ldS = DM; ldD = DM; tx = 64;
    } else if (b < 32768) {
        b -= 16384; src = wf1; dst = df1; ldS = DFF; ldD = DM; tx = 256;
    } else {
        b -= 32768; src = wf2; dst = df2; ldS = DM; ldD = DFF; tx = 64;
    }
    const int bx = b % tx, by = b / tx;
    int r0 = by << 6, c0 = bx << 6;
    int tid = threadIdx.x;
#pragma unroll
    for (int it = 0; it < 4; ++it) {
        int e = (tid + it * 256) * 4;
        int rr = e >> 6, cc = e & 63;
        float4v v = *(const float4v*)(src + (size_t)(r0 + rr) * ldS + c0 + cc);
#pragma unroll
        for (int j = 0; j < 4; ++j) tl[rr * 66 + cc + j] = f2b(v[j]);
    }
    __syncthreads();
#pragma unroll
    for (int it = 0; it < 2; ++it) {
        int e = tid + it * 256;
        int oc = e >> 3;
        int k8 = (e & 7) * 8;
        ushort8v w;
#pragma unroll
        for (int j = 0; j < 8; ++j) w[j] = tl[(k8 + j) * 66 + oc];
        *(ushort8v*)(dst + (size_t)(c0 + oc) * ldD + r0 + k8) = w;
    }
}

// ---------------- bf16 transpose (V -> vT) ----------------
__global__ __launch_bounds__(256) void transpose_bf(const unsigned short* __restrict__ src,
                                                    unsigned short* __restrict__ dst,
                                                    int ldS, int ldD) {
    __shared__ unsigned short tl[64 * 66];
    int r0 = blockIdx.y << 6, c0 = blockIdx.x << 6;
    int tid = threadIdx.x;
#pragma unroll
    for (int it = 0; it < 4; ++it) {
        int e = (tid + it * 256) * 4;
        int rr = e >> 6, cc = e & 63;
        ushort4v v = *(const ushort4v*)(src + (size_t)(r0 + rr) * ldS + c0 + cc);
#pragma unroll
        for (int j = 0; j < 4; ++j) tl[rr * 66 + cc + j] = v[j];
    }
    __syncthreads();
#pragma unroll
    for (int it = 0; it < 2; ++it) {
        int e = tid + it * 256;
        int oc = e >> 3;
        int k8 = (e & 7) * 8;
        ushort8v w;
#pragma unroll
        for (int j = 0; j < 8; ++j) w[j] = tl[(k8 + j) * 66 + oc];
        *(ushort8v*)(dst + (size_t)(c0 + oc) * ldD + r0 + k8) = w;
    }
}

// ---------------- 256x256 GEMM, 4 barriers / 2 K-tiles (r12 loop; r16: runtime split) ----------------
// Loop/schedule = r12 exactly (proven best: 41.4%). r16 change is only the split-K plumbing:
// split count is now a runtime log2 (ksh) per param set -> sp = b / nwg, Keff = Kfull >> ksh.
// Lets merged2 run FFN2 split-4 (B-panel per split 2MB -> L2-resident like FFN1's) alongside
// WO split-2, FFN2-first for packing.
#define MF(a, b, c) __builtin_amdgcn_mfma_f32_16x16x32_bf16(a, b, c, 0, 0, 0)
#define BARR() __builtin_amdgcn_s_barrier()

#define RDA4(BUF, MB)                                                                    \
    _Pragma("unroll") for (int i2 = 0; i2 < 4; ++i2) {                                   \
        af[(MB) + i2][0] = *(const short8*)((BUF) + (arowb + ((MB) + i2) * 16) * 64 + ca0);\
        af[(MB) + i2][1] = *(const short8*)((BUF) + (arowb + ((MB) + i2) * 16) * 64 + ca1);\
    }
#define RDB4(BUF)                                                                        \
    _Pragma("unroll") for (int j2 = 0; j2 < 4; ++j2) {                                   \
        bf[j2][0] = *(const short8*)((BUF) + (brow + j2 * 16) * 64 + ca0);               \
        bf[j2][1] = *(const short8*)((BUF) + (brow + j2 * 16) * 64 + ca1);               \
    }
#define MMQ(MB, NB)                                                                      \
    __builtin_amdgcn_s_setprio(1);                                                       \
    _Pragma("unroll") for (int kk = 0; kk < 2; ++kk)                                     \
        _Pragma("unroll") for (int i2 = 0; i2 < 4; ++i2)                                 \
            _Pragma("unroll") for (int j2 = 0; j2 < 2; ++j2)                             \
                acc[(MB) + i2][(NB) + j2] =                                              \
                    MF(af[(MB) + i2][kk], bf[(NB) + j2][kk], acc[(MB) + i2][(NB) + j2]); \
    __builtin_amdgcn_s_setprio(0)

__global__ __launch_bounds__(512, 1) void gemm2sq(
    int M, int nwg0,
    const unsigned short* __restrict__ A_0, int K_0, int ksh_0,
    const unsigned short* __restrict__ BT_0, void* __restrict__ C_0, int N_0, int ldc_0,
    const float* __restrict__ bias_0, int epi_0,
    const unsigned short* __restrict__ A_1, int K_1, int ksh_1,
    const unsigned short* __restrict__ BT_1, void* __restrict__ C_1, int N_1, int ldc_1,
    const float* __restrict__ bias_1, int epi_1) {
    __shared__ unsigned short aL[2][256 * 64];  // 64 KB
    __shared__ unsigned short bL[2][256 * 64];  // 64 KB

    int b = blockIdx.x;
    const unsigned short *A, *BT;
    void* Cout;
    int N, ldc, epi, Kfull, ksh;
    const float* bias;
    if (b < nwg0) {
        A = A_0; Kfull = K_0; ksh = ksh_0; BT = BT_0; Cout = C_0; N = N_0; ldc = ldc_0; bias = bias_0; epi = epi_0;
    } else {
        b -= nwg0;
        A = A_1; Kfull = K_1; ksh = ksh_1; BT = BT_1; Cout = C_1; N = N_1; ldc = ldc_1; bias = bias_1; epi = epi_1;
    }

    const int nby = M >> 8, nbx = N >> 8;
    const int nwg = nby * nbx;
    const int sp = b / nwg;
    b -= sp * nwg;
    const int Keff = Kfull >> ksh;
    const int koff = sp * Keff;

    const int slabw = nbx >> 3;
    const int xcd = b & 7;
    const int jj = b >> 3;
    const int bx = xcd * slabw + jj / nby;
    const int by = jj % nby;
    const int bm0 = by << 8, bn0 = bx << 8;

    const int tid = threadIdx.x, lane = tid & 63, wave = tid >> 6;
    const int wm = wave >> 2, wn = wave & 3;
    const int l15 = lane & 15, kl = lane >> 4;

    const int rh = tid >> 3;
    const int cb_s = (tid & 7) << 4;
    const int kx = (cb_s ^ ((rh & 7) << 4)) >> 1;

    const unsigned short* Abase = A + (size_t)(bm0 + rh) * Kfull + koff + kx;
    const unsigned short* Bbase = BT + (size_t)(bn0 + rh) * Kfull + koff + kx;

    auto stageA = [&](int v, int h) {
        const unsigned short* g = Abase + (size_t)v * 64 + (size_t)(h * 128) * Kfull;
        char* l = (char*)aL[v & 1] + h * 16384 + tid * 16;
        gload_lds16(g, l);
        gload_lds16(g + (size_t)64 * Kfull, l + 8192);
    };
    auto stageB = [&](int v, int h) {
        const unsigned short* g = Bbase + (size_t)v * 64 + (size_t)(h * 128) * Kfull;
        char* l = (char*)bL[v & 1] + h * 16384 + tid * 16;
        gload_lds16(g, l);
        gload_lds16(g + (size_t)64 * Kfull, l + 8192);
    };

    const int arowb = wm * 128 + l15;
    const int brow = wn * 64 + l15;
    const int sa = (l15 & 7) << 4;
    const int ca0 = ((kl * 16) ^ sa) >> 1;
    const int ca1 = ((64 + kl * 16) ^ sa) >> 1;

    f32x4 acc[8][4];
#pragma unroll
    for (int i = 0; i < 8; ++i)
#pragma unroll
        for (int j2 = 0; j2 < 4; ++j2) acc[i][j2] = (f32x4){0.f, 0.f, 0.f, 0.f};

    short8 af[8][2], bf[4][2];

    // prologue: tile0 (A,B) + B(1); wait tile0 (B(1)'s 4 loads stay in flight)
    stageA(0, 0); stageA(0, 1); stageB(0, 0); stageB(0, 1); stageB(1, 0); stageB(1, 1);
    asm volatile("s_waitcnt vmcnt(4)" ::: "memory");
    BARR();

    const int NI = (Keff >> 6) >> 1;
    for (int t2 = 0; t2 < NI; ++t2) {
        const int u = t2 << 1;
        const bool last = (t2 == NI - 1);
        const unsigned short* a0 = aL[0];
        const unsigned short* b0 = bL[0];
        const unsigned short* a1 = aL[1];
        const unsigned short* b1 = bL[1];

        // P1: read tile u fully; stage A(u+1) both halves; MFMA M0-3
        RDA4(a0, 0); RDA4(a0, 4); RDB4(b0);
        stageA(u + 1, 0); stageA(u + 1, 1);
        MMQ(0, 0); MMQ(0, 2);
        BARR();
        // P2: stage B(u+2); MFMA M4-7; vmcnt gates tile u+1
        if (!last) { stageB(u + 2, 0); stageB(u + 2, 1); }
        MMQ(4, 0); MMQ(4, 2);
        if (last) { asm volatile("s_waitcnt vmcnt(0)" ::: "memory"); }
        else      { asm volatile("s_waitcnt vmcnt(4)" ::: "memory"); }
        BARR();

        // P3: read tile u+1 fully; stage A(u+2); MFMA M0-3
        RDA4(a1, 0); RDA4(a1, 4); RDB4(b1);
        if (!last) { stageA(u + 2, 0); stageA(u + 2, 1); }
        MMQ(0, 0); MMQ(0, 2);
        BARR();
        // P4: stage B(u+3); MFMA M4-7; vmcnt gates tile u+2
        if (!last) { stageB(u + 3, 0); stageB(u + 3, 1); }
        MMQ(4, 0); MMQ(4, 2);
        if (!last) { asm volatile("s_waitcnt vmcnt(4)" ::: "memory"); }
        BARR();
    }

    // epilogue (runtime epi: 0=bf16, 1=f32 split partial, 2=+bias gelu bf16)
    const int r0 = bm0 + wm * 128 + kl * 4;
    const int c0g = bn0 + wn * 64 + l15;
#pragma unroll
    for (int mi = 0; mi < 8; ++mi) {
#pragma unroll
        for (int nj = 0; nj < 4; ++nj) {
            int col = c0g + nj * 16;
#pragma unroll
            for (int r = 0; r < 4; ++r) {
                int row = r0 + mi * 16 + r;
                float v = acc[mi][nj][r];
                if (epi == 0) {
                    ((unsigned short*)Cout)[(size_t)row * ldc + col] = f2b(v);
                } else if (epi == 1) {
                    ((float*)Cout)[(size_t)sp * M * N + (size_t)row * ldc + col] = v;
                } else {
                    v += bias[col];
                    float z = 1.5957691216f * (v + 0.044715f * v * v * v);
                    float g = v / (1.0f + __expf(-z));
                    ((unsigned short*)Cout)[(size_t)row * ldc + col] = f2b(g);
                }
            }
        }
    }
}

// ---------------- final reduce: out = fp0..3 + wp0..1 + b_ffn_o ----------------
__global__ __launch_bounds__(256) void final_reduce(const float* __restrict__ fp,
                                                    const float* __restrict__ wp,
                                                    const float* __restrict__ bias,
                                                    float* __restrict__ out) {
    size_t i = (size_t)blockIdx.x * 256 + threadIdx.x;
    const size_t stride = (size_t)SEQ * DM / 4;
    const float4v* b4 = (const float4v*)bias;
    float4v v = b4[i & (DM / 4 - 1)];
#pragma unroll
    for (int s = 0; s < 4; ++s) v += ((const float4v*)fp)[s * stride + i];
#pragma unroll
    for (int s = 0; s < 2; ++s) v += ((const float4v*)wp)[s * stride + i];
    ((float4v*)out)[i] = v;
}

// ---------------- flash attention ----------------
__global__ __launch_bounds__(256, 2) void attn_kernel(const unsigned short* __restrict__ qkv,
                                                      const unsigned short* __restrict__ vT,
                                                      const float* __restrict__ bias,
                                                      unsigned short* __restrict__ attn_vec) {
    __shared__ unsigned short kL[64 * 264];
    __shared__ unsigned short vL[256 * 72];
    __shared__ unsigned short pL[4][16 * 72];

    int qb = blockIdx.x, head = blockIdx.y;
    int tid = threadIdx.x, lane = tid & 63, wave = tid >> 6;
    int q16 = lane & 15, q4 = lane >> 4;

    short8 qf[8];
    {
        const unsigned short* qp =
            qkv + (size_t)(qb * 64 + wave * 16 + q16) * (3 * DM) + head * DHEAD + (q4 << 3);
#pragma unroll
        for (int kk = 0; kk < 8; ++kk) qf[kk] = *(const short8*)(qp + kk * 32);
    }

    f32x4 o[16];
#pragma unroll
    for (int d = 0; d < 16; ++d) o[d] = (f32x4){0.f, 0.f, 0.f, 0.f};
    float m_run[4] = {-INFINITY, -INFINITY, -INFINITY, -INFINITY};
    float l_run[4] = {0.f, 0.f, 0.f, 0.f};
    int qrow0 = qb * 64 + wave * 16 + q4 * 4;

    for (int t = 0; t <= qb; ++t) {
        int kv0 = t * 64;
#pragma unroll
        for (int rr = 0; rr < 8; ++rr) {
            int i = tid + rr * 256;
            int row = i >> 5, c8 = (i & 31) << 3;
            *(ushort8v*)(kL + row * 264 + c8) =
                *(const ushort8v*)(qkv + (size_t)(kv0 + row) * (3 * DM) + DM + head * DHEAD + c8);
        }
#pragma unroll
        for (int rr = 0; rr < 8; ++rr) {
            int i = tid + rr * 256;
            int d = i >> 3, c8 = (i & 7) << 3;
            *(ushort8v*)(vL + d * 72 + c8) =
                *(const ushort8v*)(vT + (size_t)(head * DHEAD + d) * SEQ + kv0 + c8);
        }
        __syncthreads();

        f32x4 s[4];
#pragma unroll
        for (int c = 0; c < 4; ++c) s[c] = (f32x4){0.f, 0.f, 0.f, 0.f};
#pragma unroll
        for (int kk = 0; kk < 8; ++kk) {
#pragma unroll
            for (int c = 0; c < 4; ++c) {
                short8 kf = *(const short8*)(kL + (c * 16 + q16) * 264 + kk * 32 + (q4 << 3));
                s[c] = __builtin_amdgcn_mfma_f32_16x16x32_bf16(qf[kk], kf, s[c], 0, 0, 0);
            }
        }

        bool diag = (t == qb);
#pragma unroll
        for (int r = 0; r < 4; ++r) {
            int qr = qrow0 + r;
            float sv[4];
#pragma unroll
            for (int c = 0; c < 4; ++c) {
                float vv = s[c][r] * 0.0625f + bias[(size_t)qr * SEQ + kv0 + c * 16 + q16];
                if (diag && (kv0 + c * 16 + q16) > qr) vv = -1e30f;
                sv[c] = vv;
            }
            float m = fmaxf(fmaxf(sv[0], sv[1]), fmaxf(sv[2], sv[3]));
#pragma unroll
            for (int off = 1; off < 16; off <<= 1) m = fmaxf(m, __shfl_xor(m, off));
            float mn = fmaxf(m_run[r], m);
            float alpha = __expf(m_run[r] - mn);
            float psum = 0.f;
#pragma unroll
            for (int c = 0; c < 4; ++c) {
                float p = __expf(sv[c] - mn);
                psum += p;
                pL[wave][(q4 * 4 + r) * 72 + c * 16 + q16] = f2b(p);
            }
#pragma unroll
            for (int off = 1; off < 16; off <<= 1) psum += __shfl_xor(psum, off);
            l_run[r] = l_run[r] * alpha + psum;
            m_run[r] = mn;
#pragma unroll
            for (int d = 0; d < 16; ++d) o[d][r] *= alpha;
        }

#pragma unroll
        for (int ks = 0; ks < 2; ++ks) {
            short8 pa = *(const short8*)(pL[wave] + q16 * 72 + ks * 32 + (q4 << 3));
#pragma unroll
            for (int d = 0; d < 16; ++d) {
                short8 vb = *(const short8*)(vL + (d * 16 + q16) * 72 + ks * 32 + (q4 << 3));
                o[d] = __builtin_amdgcn_mfma_f32_16x16x32_bf16(pa, vb, o[d], 0, 0, 0);
            }
        }
        __syncthreads();
    }

#pragma unroll
    for (int r = 0; r < 4; ++r) {
        float inv = 1.0f / l_run[r];
#pragma unroll
        for (int d = 0; d < 16; ++d)
            attn_vec[(size_t)(qrow0 + r) * DM + head * DHEAD + d * 16 + q16] = f2b(o[d][r] * inv);
    }
}

// ---------------- launch ----------------
extern "C" void kernel_launch(void* const* d_in, const int* in_sizes, int n_in,
                              void* d_out, int out_size, void* d_ws, size_t ws_size,
                              hipStream_t stream) {
    const float* x = (const float*)d_in[0];
    const float* attn_bias = (const float*)d_in[1];
    const float* ln_scale = (const float*)d_in[2];
    const float* ln_offset = (const float*)d_in[3];
    const float* wq = (const float*)d_in[4];
    const float* wk = (const float*)d_in[5];
    const float* wv = (const float*)d_in[6];
    const float* wo = (const float*)d_in[7];
    const float* w_ffn = (const float*)d_in[8];
    const float* b_ffn = (const float*)d_in[9];
    const float* w_ffn_o = (const float*)d_in[10];
    const float* b_ffn_o = (const float*)d_in[11];
    float* out = (float*)d_out;

    char* p = (char*)d_ws;
    unsigned short* WT_qkv = (unsigned short*)p; p += (size_t)3 * DM * DM * 2;   // 96MB
    unsigned short* WT_o = (unsigned short*)p;   p += (size_t)DM * DM * 2;       // 32MB
    unsigned short* WT_f1 = (unsigned short*)p;  p += (size_t)DFF * DM * 2;      // 128MB
    unsigned short* WT_f2 = (unsigned short*)p;  p += (size_t)DM * DFF * 2;      // 128MB
    unsigned short* hB = (unsigned short*)p;     p += (size_t)SEQ * DM * 2;
    unsigned short* qkvB = (unsigned short*)p;   p += (size_t)SEQ * 3 * DM * 2;
    unsigned short* vTB = (unsigned short*)p;    p += (size_t)DM * SEQ * 2;
    unsigned short* avB = (unsigned short*)p;    p += (size_t)SEQ * DM * 2;
    unsigned short* ffB = (unsigned short*)p;    p += (size_t)SEQ * DFF * 2;

    // split-K partials alias dead weight buffers:
    // fp (FFN2, 4 splits x 32MB = 128MB) -> WT_f1 (consumed by FFN1 in merged1)
    // wp (WO, 2 splits x 32MB = 64MB)    -> WT_qkv (consumed by QKV in merged1, 96MB)
    float* fp = (float*)WT_f1;
    float* wp = (float*)WT_qkv;

    // LN + all 6 weight transposes: one launch (2048 + 49152 = 51200 blocks)
    pre_all<<<51200, 256, 0, stream>>>(x, ln_scale, ln_offset, hB,
                                       wq, wk, wv, wo, w_ffn, w_ffn_o,
                                       WT_qkv, WT_o, WT_f1, WT_f2);

    // merged QKV (384 blocks, epi 0) + FFN1 (512 blocks, epi 2): 896 blocks
    gemm2sq<<<896, 512, 0, stream>>>(
        SEQ, 384,
        hB, DM, 0, WT_qkv, qkvB, 3 * DM, 3 * DM, nullptr, 0,
        hB, DM, 0, WT_f1, ffB, DFF, DFF, b_ffn, 2);

    transpose_bf<<<dim3(DM / 64, SEQ / 64), 256, 0, stream>>>(qkvB + 2 * DM, vTB, 3 * DM, SEQ);

    attn_kernel<<<dim3(SEQ / 64, NHEADS), 256, 0, stream>>>(qkvB, vTB, attn_bias, avB);

    // merged FFN2 (split-4, 512 blocks, FIRST for packing) + WO (split-2, 256 blocks): 768
    gemm2sq<<<768, 512, 0, stream>>>(
        SEQ, 512,
        ffB, DFF, 2, WT_f2, fp, DM, DM, nullptr, 1,
        avB, DM, 1, WT_o, wp, DM, DM, nullptr, 1);

    final_reduce<<<(SEQ * DM / 4) / 256, 256, 0, stream>>>(fp, wp, b_ffn_o, out);
}

// Round 17
// 1195.399 us; speedup vs baseline: 1.0203x; 1.0203x over previous
//
#include <hip/hip_runtime.h>
#include <stdint.h>

#define SEQ 2048
#define DM 4096
#define NHEADS 16
#define DHEAD 256
#define DFF 16384

typedef __attribute__((ext_vector_type(8))) short short8;
typedef __attribute__((ext_vector_type(4))) float f32x4;
typedef __attribute__((ext_vector_type(4))) float float4v;
typedef __attribute__((ext_vector_type(4))) unsigned short ushort4v;
typedef __attribute__((ext_vector_type(8))) unsigned short ushort8v;

__device__ __forceinline__ unsigned short f2b(float f) {
    uint32_t u = __builtin_bit_cast(uint32_t, f);
    u = (u + 0x7FFFu + ((u >> 16) & 1u)) >> 16;
    return (unsigned short)u;
}

__device__ __forceinline__ void gload_lds16(const void* g, void* l) {
    __builtin_amdgcn_global_load_lds((const __attribute__((address_space(1))) void*)g,
                                     (__attribute__((address_space(3))) void*)l, 16, 0, 0);
}

// ---------------- pre: LN + ALL weight transposes in one flat-grid launch ----------------
__global__ __launch_bounds__(256) void pre_all(
    const float* __restrict__ x, const float* __restrict__ sc, const float* __restrict__ of,
    unsigned short* __restrict__ h,
    const float* __restrict__ wq, const float* __restrict__ wk, const float* __restrict__ wv,
    const float* __restrict__ wo, const float* __restrict__ wf1, const float* __restrict__ wf2,
    unsigned short* __restrict__ dqkv, unsigned short* __restrict__ dwo,
    unsigned short* __restrict__ df1, unsigned short* __restrict__ df2) {
    __shared__ unsigned short tl[64 * 66];
    __shared__ float rs[4], rs2[4];
    int b = blockIdx.x;
    if (b < SEQ) {
        int row = b;
        int tid = threadIdx.x, lane = tid & 63, wave = tid >> 6;
        const float4v* xr = (const float4v*)(x + (size_t)row * DM);
        float4v v[4];
        float s = 0.f, s2 = 0.f;
#pragma unroll
        for (int i = 0; i < 4; ++i) {
            v[i] = xr[tid + i * 256];
#pragma unroll
            for (int j = 0; j < 4; ++j) { s += v[i][j]; s2 += v[i][j] * v[i][j]; }
        }
#pragma unroll
        for (int o = 1; o < 64; o <<= 1) { s += __shfl_xor(s, o); s2 += __shfl_xor(s2, o); }
        if (lane == 0) { rs[wave] = s; rs2[wave] = s2; }
        __syncthreads();
        s = rs[0] + rs[1] + rs[2] + rs[3];
        s2 = rs2[0] + rs2[1] + rs2[2] + rs2[3];
        float mean = s * (1.0f / DM);
        float var = s2 * (1.0f / DM) - mean * mean;
        float inv = rsqrtf(var + 1e-5f);
#pragma unroll
        for (int i = 0; i < 4; ++i) {
            int c = (tid + i * 256) * 4;
            ushort4v o4;
#pragma unroll
            for (int j = 0; j < 4; ++j)
                o4[j] = f2b((v[i][j] - mean) * inv * sc[c + j] + of[c + j]);
            *(ushort4v*)(h + (size_t)row * DM + c) = o4;
        }
        return;
    }
    b -= SEQ;
    const float* src;
    unsigned short* dst;
    int ldS, ldD, tx;
    if (b < 12288) {
        int w = b >> 12;
        b &= 4095;
        src = (w == 0) ? wq : (w == 1) ? wk : wv;
        dst = dqkv + (size_t)w * DM * DM;
        ldS = DM; ldD = DM; tx = 64;
    } else if (b < 16384) {
        b -= 12288; src = wo; dst = dwo; ldS = DM; ldD = DM; tx = 64;
    } else if (b < 32768) {
        b -= 16384; src = wf1; dst = df1; ldS = DFF; ldD = DM; tx = 256;
    } else {
        b -= 32768; src = wf2; dst = df2; ldS = DM; ldD = DFF; tx = 64;
    }
    const int bx = b % tx, by = b / tx;
    int r0 = by << 6, c0 = bx << 6;
    int tid = threadIdx.x;
#pragma unroll
    for (int it = 0; it < 4; ++it) {
        int e = (tid + it * 256) * 4;
        int rr = e >> 6, cc = e & 63;
        float4v v = *(const float4v*)(src + (size_t)(r0 + rr) * ldS + c0 + cc);
#pragma unroll
        for (int j = 0; j < 4; ++j) tl[rr * 66 + cc + j] = f2b(v[j]);
    }
    __syncthreads();
#pragma unroll
    for (int it = 0; it < 2; ++it) {
        int e = tid + it * 256;
        int oc = e >> 3;
        int k8 = (e & 7) * 8;
        ushort8v w;
#pragma unroll
        for (int j = 0; j < 8; ++j) w[j] = tl[(k8 + j) * 66 + oc];
        *(ushort8v*)(dst + (size_t)(c0 + oc) * ldD + r0 + k8) = w;
    }
}

// ---------------- bf16 transpose (V -> vT) ----------------
__global__ __launch_bounds__(256) void transpose_bf(const unsigned short* __restrict__ src,
                                                    unsigned short* __restrict__ dst,
                                                    int ldS, int ldD) {
    __shared__ unsigned short tl[64 * 66];
    int r0 = blockIdx.y << 6, c0 = blockIdx.x << 6;
    int tid = threadIdx.x;
#pragma unroll
    for (int it = 0; it < 4; ++it) {
        int e = (tid + it * 256) * 4;
        int rr = e >> 6, cc = e & 63;
        ushort4v v = *(const ushort4v*)(src + (size_t)(r0 + rr) * ldS + c0 + cc);
#pragma unroll
        for (int j = 0; j < 4; ++j) tl[rr * 66 + cc + j] = v[j];
    }
    __syncthreads();
#pragma unroll
    for (int it = 0; it < 2; ++it) {
        int e = tid + it * 256;
        int oc = e >> 3;
        int k8 = (e & 7) * 8;
        ushort8v w;
#pragma unroll
        for (int j = 0; j < 8; ++j) w[j] = tl[(k8 + j) * 66 + oc];
        *(ushort8v*)(dst + (size_t)(c0 + oc) * ldD + r0 + k8) = w;
    }
}

// ---------------- 256x256 GEMM, 4 barriers / 2 K-tiles (r12 - proven best) ----------------
#define MF(a, b, c) __builtin_amdgcn_mfma_f32_16x16x32_bf16(a, b, c, 0, 0, 0)
#define BARR() __builtin_amdgcn_s_barrier()

#define RDA4(BUF, MB)                                                                    \
    _Pragma("unroll") for (int i2 = 0; i2 < 4; ++i2) {                                   \
        af[(MB) + i2][0] = *(const short8*)((BUF) + (arowb + ((MB) + i2) * 16) * 64 + ca0);\
        af[(MB) + i2][1] = *(const short8*)((BUF) + (arowb + ((MB) + i2) * 16) * 64 + ca1);\
    }
#define RDB4(BUF)                                                                        \
    _Pragma("unroll") for (int j2 = 0; j2 < 4; ++j2) {                                   \
        bf[j2][0] = *(const short8*)((BUF) + (brow + j2 * 16) * 64 + ca0);               \
        bf[j2][1] = *(const short8*)((BUF) + (brow + j2 * 16) * 64 + ca1);               \
    }
#define MMQ(MB, NB)                                                                      \
    __builtin_amdgcn_s_setprio(1);                                                       \
    _Pragma("unroll") for (int kk = 0; kk < 2; ++kk)                                     \
        _Pragma("unroll") for (int i2 = 0; i2 < 4; ++i2)                                 \
            _Pragma("unroll") for (int j2 = 0; j2 < 2; ++j2)                             \
                acc[(MB) + i2][(NB) + j2] =                                              \
                    MF(af[(MB) + i2][kk], bf[(NB) + j2][kk], acc[(MB) + i2][(NB) + j2]); \
    __builtin_amdgcn_s_setprio(0)

template <int SPLIT>
__global__ __launch_bounds__(512, 1) void gemm2sq(
    int M, int nwg0,
    const unsigned short* __restrict__ A_0, int K_0, const unsigned short* __restrict__ BT_0,
    void* __restrict__ C_0, int N_0, int ldc_0, const float* __restrict__ bias_0, int epi_0,
    const unsigned short* __restrict__ A_1, int K_1, const unsigned short* __restrict__ BT_1,
    void* __restrict__ C_1, int N_1, int ldc_1, const float* __restrict__ bias_1, int epi_1) {
    __shared__ unsigned short aL[2][256 * 64];  // 64 KB
    __shared__ unsigned short bL[2][256 * 64];  // 64 KB

    int b = blockIdx.x;
    const unsigned short *A, *BT;
    void* Cout;
    int N, ldc, epi, Kfull;
    const float* bias;
    if (b < nwg0) {
        A = A_0; Kfull = K_0; BT = BT_0; Cout = C_0; N = N_0; ldc = ldc_0; bias = bias_0; epi = epi_0;
    } else {
        b -= nwg0;
        A = A_1; Kfull = K_1; BT = BT_1; Cout = C_1; N = N_1; ldc = ldc_1; bias = bias_1; epi = epi_1;
    }

    const int nby = M >> 8, nbx = N >> 8;
    const int nwg = nby * nbx;
    int sp = 0;
    if (SPLIT == 2) { sp = (b >= nwg) ? 1 : 0; b -= sp * nwg; }
    const int Keff = Kfull / SPLIT;
    const int koff = sp * Keff;

    const int slabw = nbx >> 3;
    const int xcd = b & 7;
    const int jj = b >> 3;
    const int bx = xcd * slabw + jj / nby;
    const int by = jj % nby;
    const int bm0 = by << 8, bn0 = bx << 8;

    const int tid = threadIdx.x, lane = tid & 63, wave = tid >> 6;
    const int wm = wave >> 2, wn = wave & 3;
    const int l15 = lane & 15, kl = lane >> 4;

    const int rh = tid >> 3;
    const int cb_s = (tid & 7) << 4;
    const int kx = (cb_s ^ ((rh & 7) << 4)) >> 1;

    const unsigned short* Abase = A + (size_t)(bm0 + rh) * Kfull + koff + kx;
    const unsigned short* Bbase = BT + (size_t)(bn0 + rh) * Kfull + koff + kx;

    auto stageA = [&](int v, int h) {
        const unsigned short* g = Abase + (size_t)v * 64 + (size_t)(h * 128) * Kfull;
        char* l = (char*)aL[v & 1] + h * 16384 + tid * 16;
        gload_lds16(g, l);
        gload_lds16(g + (size_t)64 * Kfull, l + 8192);
    };
    auto stageB = [&](int v, int h) {
        const unsigned short* g = Bbase + (size_t)v * 64 + (size_t)(h * 128) * Kfull;
        char* l = (char*)bL[v & 1] + h * 16384 + tid * 16;
        gload_lds16(g, l);
        gload_lds16(g + (size_t)64 * Kfull, l + 8192);
    };

    const int arowb = wm * 128 + l15;
    const int brow = wn * 64 + l15;
    const int sa = (l15 & 7) << 4;
    const int ca0 = ((kl * 16) ^ sa) >> 1;
    const int ca1 = ((64 + kl * 16) ^ sa) >> 1;

    f32x4 acc[8][4];
#pragma unroll
    for (int i = 0; i < 8; ++i)
#pragma unroll
        for (int j2 = 0; j2 < 4; ++j2) acc[i][j2] = (f32x4){0.f, 0.f, 0.f, 0.f};

    short8 af[8][2], bf[4][2];

    // prologue: tile0 (A,B) + B(1); wait tile0 (B(1)'s 4 loads stay in flight)
    stageA(0, 0); stageA(0, 1); stageB(0, 0); stageB(0, 1); stageB(1, 0); stageB(1, 1);
    asm volatile("s_waitcnt vmcnt(4)" ::: "memory");
    BARR();

    const int NI = (Keff >> 6) >> 1;
    for (int t2 = 0; t2 < NI; ++t2) {
        const int u = t2 << 1;
        const bool last = (t2 == NI - 1);
        const unsigned short* a0 = aL[0];
        const unsigned short* b0 = bL[0];
        const unsigned short* a1 = aL[1];
        const unsigned short* b1 = bL[1];

        // P1: read tile u fully; stage A(u+1) both halves; MFMA M0-3
        RDA4(a0, 0); RDA4(a0, 4); RDB4(b0);
        stageA(u + 1, 0); stageA(u + 1, 1);
        MMQ(0, 0); MMQ(0, 2);
        BARR();
        // P2: stage B(u+2); MFMA M4-7; vmcnt gates tile u+1
        if (!last) { stageB(u + 2, 0); stageB(u + 2, 1); }
        MMQ(4, 0); MMQ(4, 2);
        if (last) { asm volatile("s_waitcnt vmcnt(0)" ::: "memory"); }
        else      { asm volatile("s_waitcnt vmcnt(4)" ::: "memory"); }
        BARR();

        // P3: read tile u+1 fully; stage A(u+2); MFMA M0-3
        RDA4(a1, 0); RDA4(a1, 4); RDB4(b1);
        if (!last) { stageA(u + 2, 0); stageA(u + 2, 1); }
        MMQ(0, 0); MMQ(0, 2);
        BARR();
        // P4: stage B(u+3); MFMA M4-7; vmcnt gates tile u+2
        if (!last) { stageB(u + 3, 0); stageB(u + 3, 1); }
        MMQ(4, 0); MMQ(4, 2);
        if (!last) { asm volatile("s_waitcnt vmcnt(4)" ::: "memory"); }
        BARR();
    }

    // epilogue (runtime epi: 0=bf16, 1=f32 split partial, 2=+bias gelu bf16)
    const int r0 = bm0 + wm * 128 + kl * 4;
    const int c0g = bn0 + wn * 64 + l15;
#pragma unroll
    for (int mi = 0; mi < 8; ++mi) {
#pragma unroll
        for (int nj = 0; nj < 4; ++nj) {
            int col = c0g + nj * 16;
#pragma unroll
            for (int r = 0; r < 4; ++r) {
                int row = r0 + mi * 16 + r;
                float v = acc[mi][nj][r];
                if (epi == 0) {
                    ((unsigned short*)Cout)[(size_t)row * ldc + col] = f2b(v);
                } else if (epi == 1) {
                    ((float*)Cout)[(size_t)sp * M * N + (size_t)row * ldc + col] = v;
                } else {
                    v += bias[col];
                    float z = 1.5957691216f * (v + 0.044715f * v * v * v);
                    float g = v / (1.0f + __expf(-z));
                    ((unsigned short*)Cout)[(size_t)row * ldc + col] = f2b(g);
                }
            }
        }
    }
}

// ---------------- final reduce ----------------
__global__ __launch_bounds__(256) void final_reduce(const float* __restrict__ fp,
                                                    const float* __restrict__ wp,
                                                    const float* __restrict__ bias,
                                                    float* __restrict__ out) {
    size_t i = (size_t)blockIdx.x * 256 + threadIdx.x;
    const float4v* f0 = (const float4v*)fp;
    const float4v* f1 = (const float4v*)(fp + (size_t)SEQ * DM);
    const float4v* w0 = (const float4v*)wp;
    const float4v* w1 = (const float4v*)(wp + (size_t)SEQ * DM);
    const float4v* b4 = (const float4v*)bias;
    float4v v = f0[i] + f1[i] + w0[i] + w1[i] + b4[i & (DM / 4 - 1)];
    ((float4v*)out)[i] = v;
}

// ---------------- flash attention ----------------
__global__ __launch_bounds__(256, 2) void attn_kernel(const unsigned short* __restrict__ qkv,
                                                      const unsigned short* __restrict__ vT,
                                                      const float* __restrict__ bias,
                                                      unsigned short* __restrict__ attn_vec) {
    __shared__ unsigned short kL[64 * 264];
    __shared__ unsigned short vL[256 * 72];
    __shared__ unsigned short pL[4][16 * 72];

    int qb = blockIdx.x, head = blockIdx.y;
    int tid = threadIdx.x, lane = tid & 63, wave = tid >> 6;
    int q16 = lane & 15, q4 = lane >> 4;

    short8 qf[8];
    {
        const unsigned short* qp =
            qkv + (size_t)(qb * 64 + wave * 16 + q16) * (3 * DM) + head * DHEAD + (q4 << 3);
#pragma unroll
        for (int kk = 0; kk < 8; ++kk) qf[kk] = *(const short8*)(qp + kk * 32);
    }

    f32x4 o[16];
#pragma unroll
    for (int d = 0; d < 16; ++d) o[d] = (f32x4){0.f, 0.f, 0.f, 0.f};
    float m_run[4] = {-INFINITY, -INFINITY, -INFINITY, -INFINITY};
    float l_run[4] = {0.f, 0.f, 0.f, 0.f};
    int qrow0 = qb * 64 + wave * 16 + q4 * 4;

    for (int t = 0; t <= qb; ++t) {
        int kv0 = t * 64;
#pragma unroll
        for (int rr = 0; rr < 8; ++rr) {
            int i = tid + rr * 256;
            int row = i >> 5, c8 = (i & 31) << 3;
            *(ushort8v*)(kL + row * 264 + c8) =
                *(const ushort8v*)(qkv + (size_t)(kv0 + row) * (3 * DM) + DM + head * DHEAD + c8);
        }
#pragma unroll
        for (int rr = 0; rr < 8; ++rr) {
            int i = tid + rr * 256;
            int d = i >> 3, c8 = (i & 7) << 3;
            *(ushort8v*)(vL + d * 72 + c8) =
                *(const ushort8v*)(vT + (size_t)(head * DHEAD + d) * SEQ + kv0 + c8);
        }
        __syncthreads();

        f32x4 s[4];
#pragma unroll
        for (int c = 0; c < 4; ++c) s[c] = (f32x4){0.f, 0.f, 0.f, 0.f};
#pragma unroll
        for (int kk = 0; kk < 8; ++kk) {
#pragma unroll
            for (int c = 0; c < 4; ++c) {
                short8 kf = *(const short8*)(kL + (c * 16 + q16) * 264 + kk * 32 + (q4 << 3));
                s[c] = __builtin_amdgcn_mfma_f32_16x16x32_bf16(qf[kk], kf, s[c], 0, 0, 0);
            }
        }

        bool diag = (t == qb);
#pragma unroll
        for (int r = 0; r < 4; ++r) {
            int qr = qrow0 + r;
            float sv[4];
#pragma unroll
            for (int c = 0; c < 4; ++c) {
                float vv = s[c][r] * 0.0625f + bias[(size_t)qr * SEQ + kv0 + c * 16 + q16];
                if (diag && (kv0 + c * 16 + q16) > qr) vv = -1e30f;
                sv[c] = vv;
            }
            float m = fmaxf(fmaxf(sv[0], sv[1]), fmaxf(sv[2], sv[3]));
#pragma unroll
            for (int off = 1; off < 16; off <<= 1) m = fmaxf(m, __shfl_xor(m, off));
            float mn = fmaxf(m_run[r], m);
            float alpha = __expf(m_run[r] - mn);
            float psum = 0.f;
#pragma unroll
            for (int c = 0; c < 4; ++c) {
                float p = __expf(sv[c] - mn);
                psum += p;
                pL[wave][(q4 * 4 + r) * 72 + c * 16 + q16] = f2b(p);
            }
#pragma unroll
            for (int off = 1; off < 16; off <<= 1) psum += __shfl_xor(psum, off);
            l_run[r] = l_run[r] * alpha + psum;
            m_run[r] = mn;
#pragma unroll
            for (int d = 0; d < 16; ++d) o[d][r] *= alpha;
        }

#pragma unroll
        for (int ks = 0; ks < 2; ++ks) {
            short8 pa = *(const short8*)(pL[wave] + q16 * 72 + ks * 32 + (q4 << 3));
#pragma unroll
            for (int d = 0; d < 16; ++d) {
                short8 vb = *(const short8*)(vL + (d * 16 + q16) * 72 + ks * 32 + (q4 << 3));
                o[d] = __builtin_amdgcn_mfma_f32_16x16x32_bf16(pa, vb, o[d], 0, 0, 0);
            }
        }
        __syncthreads();
    }

#pragma unroll
    for (int r = 0; r < 4; ++r) {
        float inv = 1.0f / l_run[r];
#pragma unroll
        for (int d = 0; d < 16; ++d)
            attn_vec[(size_t)(qrow0 + r) * DM + head * DHEAD + d * 16 + q16] = f2b(o[d][r] * inv);
    }
}

// ---------------- launch ----------------
extern "C" void kernel_launch(void* const* d_in, const int* in_sizes, int n_in,
                              void* d_out, int out_size, void* d_ws, size_t ws_size,
                              hipStream_t stream) {
    const float* x = (const float*)d_in[0];
    const float* attn_bias = (const float*)d_in[1];
    const float* ln_scale = (const float*)d_in[2];
    const float* ln_offset = (const float*)d_in[3];
    const float* wq = (const float*)d_in[4];
    const float* wk = (const float*)d_in[5];
    const float* wv = (const float*)d_in[6];
    const float* wo = (const float*)d_in[7];
    const float* w_ffn = (const float*)d_in[8];
    const float* b_ffn = (const float*)d_in[9];
    const float* w_ffn_o = (const float*)d_in[10];
    const float* b_ffn_o = (const float*)d_in[11];
    float* out = (float*)d_out;

    char* p = (char*)d_ws;
    unsigned short* WT_qkv = (unsigned short*)p; p += (size_t)3 * DM * DM * 2;   // 96MB
    unsigned short* WT_o = (unsigned short*)p;   p += (size_t)DM * DM * 2;       // 32MB
    unsigned short* WT_f1 = (unsigned short*)p;  p += (size_t)DFF * DM * 2;      // 128MB
    unsigned short* WT_f2 = (unsigned short*)p;  p += (size_t)DM * DFF * 2;      // 128MB
    unsigned short* hB = (unsigned short*)p;     p += (size_t)SEQ * DM * 2;
    unsigned short* qkvB = (unsigned short*)p;   p += (size_t)SEQ * 3 * DM * 2;
    unsigned short* vTB = (unsigned short*)p;    p += (size_t)DM * SEQ * 2;
    unsigned short* avB = (unsigned short*)p;    p += (size_t)SEQ * DM * 2;
    unsigned short* ffB = (unsigned short*)p;    p += (size_t)SEQ * DFF * 2;

    // split-K partials alias dead weight buffers
    float* fp = (float*)WT_qkv;
    float* wp = (float*)WT_f1;

    // LN + all 6 weight transposes: one launch (2048 + 49152 = 51200 blocks)
    pre_all<<<51200, 256, 0, stream>>>(x, ln_scale, ln_offset, hB,
                                       wq, wk, wv, wo, w_ffn, w_ffn_o,
                                       WT_qkv, WT_o, WT_f1, WT_f2);

    // merged QKV (384 blocks, epi 0) + FFN1 (512 blocks, epi 2): 896 blocks
    gemm2sq<1><<<896, 512, 0, stream>>>(
        SEQ, 384,
        hB, DM, WT_qkv, qkvB, 3 * DM, 3 * DM, nullptr, 0,
        hB, DM, WT_f1, ffB, DFF, DFF, b_ffn, 2);

    transpose_bf<<<dim3(DM / 64, SEQ / 64), 256, 0, stream>>>(qkvB + 2 * DM, vTB, 3 * DM, SEQ);

    attn_kernel<<<dim3(SEQ / 64, NHEADS), 256, 0, stream>>>(qkvB, vTB, attn_bias, avB);

    // merged WO (split-K=2) + FFN2 (split-K=2): 512 blocks
    gemm2sq<2><<<512, 512, 0, stream>>>(
        SEQ, 256,
        avB, DM, WT_o, wp, DM, DM, nullptr, 1,
        ffB, DFF, WT_f2, fp, DM, DM, nullptr, 1);

    final_reduce<<<(SEQ * DM / 4) / 256, 256, 0, stream>>>(fp, wp, b_ffn_o, out);
}